// Round 1
// baseline (110.553 us; speedup 1.0000x reference)
//
#include <hip/hip_runtime.h>

// 12-byte row fragment; 4-byte aligned so the compiler can emit dwordx3.
struct F3 { float a, b, c; };

__global__ __launch_bounds__(256) void lbp_min_rot_kernel(
    const float* __restrict__ x, float* __restrict__ out, int nwin) {
    int tid = blockIdx.x * blockDim.x + threadIdx.x;
    if (tid >= nwin) return;

    // Fixed problem geometry: (B*C)=512 images of 384x384, OH=OW=128.
    const int rem = tid & 16383;          // within one image: oi*128 + oj
    const int bc  = tid >> 14;
    const int oi  = rem >> 7;
    const int oj  = rem & 127;
    const long base = ((long)bc * 384 + 3L * oi) * 384 + 3L * oj;

    const float* p = x + base;
    F3 r0 = *(const F3*)(p);
    F3 r1 = *(const F3*)(p + 384);
    F3 r2 = *(const F3*)(p + 768);
    const float w00 = r0.a, w01 = r0.b, w02 = r0.c;
    const float w10 = r1.a, w11 = r1.b, w12 = r1.c;
    const float w20 = r2.a, w21 = r2.b, w22 = r2.c;

    const float c = w11;
    const int b00 = w00 >= c, b01 = w01 >= c, b02 = w02 >= c;
    const int b10 = w10 >= c,                 b12 = w12 >= c;
    const int b20 = w20 >= c, b21 = w21 >= c, b22 = w22 >= c;

    // LBP keys of the 4 rotations (weights [[1,2,4],[8,0,16],[32,64,128]]).
    // rot1[i][j]=w[j][2-i], rot2[i][j]=w[2-i][2-j], rot3[i][j]=w[2-j][i].
    const int k0 = b00*1 + b01*2 + b02*4 + b10*8 + b12*16 + b20*32 + b21*64 + b22*128;
    const int k1 = b02*1 + b12*2 + b22*4 + b01*8 + b21*16 + b00*32 + b10*64 + b20*128;
    const int k2 = b22*1 + b21*2 + b20*4 + b12*8 + b10*16 + b02*32 + b01*64 + b00*128;
    const int k3 = b20*1 + b10*2 + b00*4 + b21*8 + b01*16 + b22*32 + b12*64 + b02*128;

    // First-occurrence argmin (matches jnp.argmin tie-breaking).
    int idx = 0, km = k0;
    if (k1 < km) { km = k1; idx = 1; }
    if (k2 < km) { km = k2; idx = 2; }
    if (k3 < km) { km = k3; idx = 3; }

    // Branch-free 4-way select of the rotated window (compiles to cndmask chains).
#define SEL4(a, b, cc, d) (idx == 0 ? (a) : idx == 1 ? (b) : idx == 2 ? (cc) : (d))
    const float o00 = SEL4(w00, w02, w22, w20);
    const float o01 = SEL4(w01, w12, w21, w10);
    const float o02 = SEL4(w02, w22, w20, w00);
    const float o10 = SEL4(w10, w01, w12, w21);
    const float o12 = SEL4(w12, w21, w10, w01);
    const float o20 = SEL4(w20, w00, w02, w22);
    const float o21 = SEL4(w21, w10, w01, w12);
    const float o22 = SEL4(w22, w20, w00, w02);
#undef SEL4

    float* q = out + base;
    *(F3*)(q)       = F3{o00, o01, o02};
    *(F3*)(q + 384) = F3{o10, w11, o12};
    *(F3*)(q + 768) = F3{o20, o21, o22};
}

extern "C" void kernel_launch(void* const* d_in, const int* in_sizes, int n_in,
                              void* d_out, int out_size, void* d_ws, size_t ws_size,
                              hipStream_t stream) {
    const float* x = (const float*)d_in[0];
    float* out = (float*)d_out;
    const int total = in_sizes[0];        // 8*64*384*384 = 75497472
    const int nwin = total / 9;           // 8388608 windows
    const int block = 256;
    const int grid = (nwin + block - 1) / block;
    lbp_min_rot_kernel<<<grid, block, 0, stream>>>(x, out, nwin);
}